// Round 10
// baseline (83.074 us; speedup 1.0000x reference)
//
#include <hip/hip_runtime.h>

#define IN_FEATS 256
#define HID 32
#define NUM_EMBED 54012
#define N_NODES 65536
#define N_EDGES 1048576
#define BATCH 4096

#define NR 256               // node ranges (dst >> 8), 256 nodes each
#define NB 256               // binsort blocks
#define EPB (N_EDGES / NB)   // 4096 edges per block
#define SEGCAP 4608          // per-range segment capacity (mean 4096, sd 64; +8 sigma)
#define CAP2 32              // bin slots per node (deg ~ Poisson(16))
#define OVF_CAP 65536
#define EMBB 422             // ceil(54012 / 128) blocks for embed@W1

typedef unsigned short u16t;
typedef unsigned int u32t;

__device__ __forceinline__ float bf2f(u16t u) {
    return __uint_as_float(((u32t)u) << 16);
}
__device__ __forceinline__ u16t f2bf(float f) {
    u32t x = __float_as_uint(f);
    return (u16t)((x + 0x7FFFu + ((x >> 16) & 1u)) >> 16);   // RNE
}

// ---------------------------------------------------------------------------
// K_init: gcur[r] = r*SEGCAP (segment cursors), ovf_cnt = 0.  1 block.
// ---------------------------------------------------------------------------
__global__ void k_init(u32t* __restrict__ gcur, int* __restrict__ ovf_cnt) {
    int t = threadIdx.x;
    gcur[t] = (u32t)t * SEGCAP;
    if (t == 0) *ovf_cnt = 0;
}

// ---------------------------------------------------------------------------
// Phase A (fused, blockIdx-dispatched):
//   [0, NB)            : binsort — LDS hist -> 1 global-atomic reservation per
//                        (block,range) -> LDS-cursor scatter into segments
//   [NB, NB+EMBB)      : tmpb = bf16(embed @ W1); 4 rows x 4 cols per thread,
//                        W1 bf16-packed in LDS, ds_read_b64 -> 16 FMA/LDS-instr
//   [NB+EMBB, +65)     : fold W2/Wfc/b2/bfc -> M1, M2, bias
// ---------------------------------------------------------------------------
__global__ void k_phaseA(const int* __restrict__ src, const int* __restrict__ dst,
                         u32t* __restrict__ gcur, u32t* __restrict__ sorted,
                         int* __restrict__ ovf_cnt, int* __restrict__ ovf,
                         const float* __restrict__ embed, const float* __restrict__ W1,
                         u16t* __restrict__ tmpb,
                         const float* __restrict__ W2, const float* __restrict__ b2,
                         const float* __restrict__ Wfc, const float* __restrict__ bfc,
                         float* __restrict__ M1, float* __restrict__ M2,
                         float* __restrict__ bias) {
    __shared__ u32t uni[4096];   // 16 KB, role-dependent
    int b = blockIdx.x;
    int t = threadIdx.x;

    if (b < NB) {
        // ---------------- binsort ----------------
        u32t* h   = uni;         // [256]
        u32t* cur = uni + 256;   // [256]
        h[t] = 0;
        __syncthreads();
        int base = b * EPB;
        for (int k = 0; k < EPB / 256; ++k) {
            int d = dst[base + k * 256 + t];
            atomicAdd(&h[d >> 8], 1u);
        }
        __syncthreads();
        cur[t] = atomicAdd(&gcur[t], h[t]);   // reserve contiguous run per range
        __syncthreads();
        for (int k = 0; k < EPB / 256; ++k) {
            int e = base + k * 256 + t;
            int s = src[e];
            int d = dst[e];
            int r = d >> 8;
            u32t p = atomicAdd(&cur[r], 1u);
            if (p < (u32t)(r + 1) * SEGCAP) {
                sorted[p] = (u32t)s | ((u32t)(d & 255) << 16);
            } else {
                int o = atomicAdd(ovf_cnt, 1);
                if (o < OVF_CAP) ovf[o] = (int)((u32t)s | ((u32t)d << 16));
            }
        }
    } else if (b < NB + EMBB) {
        // ---------------- embed @ W1 (4 rows x 4 cols / thread) ----------------
        int eb = b - NB;
        // stage W1 as packed bf16 pairs: uni[k*16 + col/2]
        for (int i = t; i < 2048; i += 256) {
            float4 v = ((const float4*)W1)[i];
            uni[i * 2 + 0] = (u32t)f2bf(v.x) | ((u32t)f2bf(v.y) << 16);
            uni[i * 2 + 1] = (u32t)f2bf(v.z) | ((u32t)f2bf(v.w) << 16);
        }
        __syncthreads();
        int rg = t >> 3;                 // 0..31
        int cg = t & 7;                  // 0..7
        int r0 = eb * 128 + rg * 4;
        int c0 = cg * 4;

        int ra = min(r0 + 0, NUM_EMBED - 1);
        int rb = min(r0 + 1, NUM_EMBED - 1);
        int rc = min(r0 + 2, NUM_EMBED - 1);
        int rd = min(r0 + 3, NUM_EMBED - 1);
        const float4* E0 = (const float4*)(embed + (size_t)ra * IN_FEATS);
        const float4* E1 = (const float4*)(embed + (size_t)rb * IN_FEATS);
        const float4* E2 = (const float4*)(embed + (size_t)rc * IN_FEATS);
        const float4* E3 = (const float4*)(embed + (size_t)rd * IN_FEATS);

        float4 a0 = {0,0,0,0}, a1 = {0,0,0,0}, a2 = {0,0,0,0}, a3 = {0,0,0,0};

        for (int k4 = 0; k4 < IN_FEATS / 4; ++k4) {
            float4 e0 = E0[k4], e1 = E1[k4], e2 = E2[k4], e3 = E3[k4];
            const u32t* wr = uni + (k4 * 4) * 16 + cg * 2;
#define WROW(OFS, S0, S1, S2, S3) { \
            u32t ux = wr[(OFS) * 16], uy = wr[(OFS) * 16 + 1]; \
            float w0 = __uint_as_float(ux << 16); \
            float w1 = __uint_as_float(ux & 0xFFFF0000u); \
            float w2 = __uint_as_float(uy << 16); \
            float w3 = __uint_as_float(uy & 0xFFFF0000u); \
            a0.x += (S0) * w0; a0.y += (S0) * w1; a0.z += (S0) * w2; a0.w += (S0) * w3; \
            a1.x += (S1) * w0; a1.y += (S1) * w1; a1.z += (S1) * w2; a1.w += (S1) * w3; \
            a2.x += (S2) * w0; a2.y += (S2) * w1; a2.z += (S2) * w2; a2.w += (S2) * w3; \
            a3.x += (S3) * w0; a3.y += (S3) * w1; a3.z += (S3) * w2; a3.w += (S3) * w3; }
            WROW(0, e0.x, e1.x, e2.x, e3.x)
            WROW(1, e0.y, e1.y, e2.y, e3.y)
            WROW(2, e0.z, e1.z, e2.z, e3.z)
            WROW(3, e0.w, e1.w, e2.w, e3.w)
#undef WROW
        }

#define ST4(R, A) \
        if ((R) < NUM_EMBED) { \
            ushort4 s4 = make_ushort4(f2bf(A.x), f2bf(A.y), f2bf(A.z), f2bf(A.w)); \
            *(ushort4*)(tmpb + (size_t)(R) * HID + c0) = s4; \
        }
        ST4(r0 + 0, a0)
        ST4(r0 + 1, a1)
        ST4(r0 + 2, a2)
        ST4(r0 + 3, a3)
#undef ST4
    } else {
        // ---------------- fold ----------------
        int r = b - NB - EMBB;   // 0..64
        int c = t;
        if (r < 32) {
            float acc = 0.f;
            for (int j = 0; j < 256; ++j) acc += W2[r * 256 + j] * Wfc[j * 256 + c];
            M1[r * 256 + c] = acc;
        } else if (r < 64) {
            int k = r - 32;
            float acc = 0.f;
            for (int j = 0; j < 256; ++j) acc += W2[k * 256 + j] * Wfc[(256 + j) * 256 + c];
            M2[k * 256 + c] = acc;
        } else {
            float acc = bfc[c];
            for (int j = 0; j < 256; ++j) acc += b2[j] * (Wfc[j * 256 + c] + Wfc[(256 + j) * 256 + c]);
            bias[c] = acc;
        }
    }
}

// ---------------------------------------------------------------------------
// Phase B (fused):
//   [0, NR)      : pack — segment -> LDS cells [256 nodes][32 u16], flush
//   [NR, NR+4096): gather — feat1[n][:] = tmpb[idx[n]][:]
// ---------------------------------------------------------------------------
__global__ void k_phaseB(const u32t* __restrict__ gcur, const u32t* __restrict__ sorted,
                         int* __restrict__ cnt, u16t* __restrict__ bins,
                         int* __restrict__ ovf_cnt, int* __restrict__ ovf,
                         const u32t* __restrict__ tmpu, const int* __restrict__ idx,
                         u32t* __restrict__ feat1u) {
    __shared__ u16t cells[NR * CAP2];   // 16 KB
    __shared__ u32t cl[NR];             // 1 KB
    int b = blockIdx.x;
    int t = threadIdx.x;
    if (b < NR) {
        int r = b;
        for (int i = t; i < NR * CAP2 / 2; i += 256) ((u32t*)cells)[i] = 0;
        cl[t] = 0;
        __syncthreads();
        u32t beg = (u32t)r * SEGCAP;
        u32t end = min(gcur[r], (u32t)(r + 1) * SEGCAP);
        for (u32t i = beg + t; i < end; i += 256) {
            u32t w = sorted[i];
            int dl = (int)(w >> 16) & 255;
            u32t p = atomicAdd(&cl[dl], 1u);
            if (p < CAP2) {
                cells[dl * CAP2 + p] = (u16t)(w & 0xFFFFu);
            } else {
                int o = atomicAdd(ovf_cnt, 1);
                u32t dfull = ((u32t)r << 8) | (u32t)dl;
                if (o < OVF_CAP) ovf[o] = (int)((w & 0xFFFFu) | (dfull << 16));
            }
        }
        __syncthreads();
        for (int i = t; i < NR * CAP2 / 2; i += 256)
            ((u32t*)(bins + ((size_t)r << 13)))[i] = ((const u32t*)cells)[i];
        cnt[(r << 8) + t] = (int)cl[t];   // true count (may exceed CAP2)
    } else {
        int i = (b - NR) * 256 + t;
        int n = i >> 4, j = i & 15;
        feat1u[((size_t)n << 4) + j] = tmpu[((size_t)idx[n] << 4) + j];
    }
}

// ---------------------------------------------------------------------------
// SpMM1: agg1[v][c] = relu(sum_slots feat1[s][c] + ovf-scan + b1[c])
// Pure store (no pre-zero). Ovf list scanned by all lanes (broadcast, ~tens).
// ---------------------------------------------------------------------------
__global__ void k_spmm1(const u16t* __restrict__ feat1,
                        const int* __restrict__ cnt, const u16t* __restrict__ bins,
                        const int* __restrict__ ovf_cnt, const int* __restrict__ ovf,
                        const float* __restrict__ b1, float* __restrict__ agg1) {
    int t = blockIdx.x * 256 + threadIdx.x;
    int v = t >> 5, c = t & 31;
    int m = cnt[v];
    const int4* cell = (const int4*)(bins + ((size_t)v << 5));
    u32t w[8];
    *(int4*)(w + 0) = cell[0];
    *(int4*)(w + 4) = cell[1];
    float va[16];
#pragma unroll
    for (int k = 0; k < 8; ++k) {
        va[2 * k + 0] = bf2f(feat1[((size_t)(w[k] & 0xFFFFu) << 5) + c]);
        va[2 * k + 1] = bf2f(feat1[((size_t)(w[k] >> 16) << 5) + c]);
    }
    float acc = 0.f;
#pragma unroll
    for (int j = 0; j < 16; ++j) acc += (m > j) ? va[j] : 0.f;
    if (m > 16) {
        u32t w2[8];
        *(int4*)(w2 + 0) = cell[2];
        *(int4*)(w2 + 4) = cell[3];
        float vb[16];
#pragma unroll
        for (int k = 0; k < 8; ++k) {
            vb[2 * k + 0] = bf2f(feat1[((size_t)(w2[k] & 0xFFFFu) << 5) + c]);
            vb[2 * k + 1] = bf2f(feat1[((size_t)(w2[k] >> 16) << 5) + c]);
        }
#pragma unroll
        for (int j = 0; j < 16; ++j) acc += (m > 16 + j) ? vb[j] : 0.f;
    }
    int total = min(*ovf_cnt, OVF_CAP);
    for (int i = 0; i < total; ++i) {
        u32t e = (u32t)ovf[i];
        if ((e >> 16) == (u32t)v)
            acc += bf2f(feat1[((size_t)(e & 0xFFFFu) << 5) + c]);
    }
    agg1[t] = fmaxf(acc + b1[c], 0.f);
}

// ---------------------------------------------------------------------------
// SpMM2 over the 8192 batch slots only (agg1 rows f32, 128B).
// ---------------------------------------------------------------------------
__global__ void k_spmm2b(const float* __restrict__ agg1,
                         const int* __restrict__ cnt, const u16t* __restrict__ bins,
                         const int* __restrict__ ovf_cnt, const int* __restrict__ ovf,
                         const int* __restrict__ g1, const int* __restrict__ g2,
                         float* __restrict__ pairfeat) {
    int t = blockIdx.x * 256 + threadIdx.x;
    int slot = t >> 5, c = t & 31;
    int v = (slot < BATCH) ? g1[slot] : g2[slot - BATCH];
    int m = cnt[v];
    const int4* cell = (const int4*)(bins + ((size_t)v << 5));
    u32t w[8];
    *(int4*)(w + 0) = cell[0];
    *(int4*)(w + 4) = cell[1];
    float va[16];
#pragma unroll
    for (int k = 0; k < 8; ++k) {
        va[2 * k + 0] = agg1[((size_t)(w[k] & 0xFFFFu) << 5) + c];
        va[2 * k + 1] = agg1[((size_t)(w[k] >> 16) << 5) + c];
    }
    float acc = 0.f;
#pragma unroll
    for (int j = 0; j < 16; ++j) acc += (m > j) ? va[j] : 0.f;
    if (m > 16) {
        u32t w2[8];
        *(int4*)(w2 + 0) = cell[2];
        *(int4*)(w2 + 4) = cell[3];
        float vb[16];
#pragma unroll
        for (int k = 0; k < 8; ++k) {
            vb[2 * k + 0] = agg1[((size_t)(w2[k] & 0xFFFFu) << 5) + c];
            vb[2 * k + 1] = agg1[((size_t)(w2[k] >> 16) << 5) + c];
        }
#pragma unroll
        for (int j = 0; j < 16; ++j) acc += (m > 16 + j) ? vb[j] : 0.f;
    }
    int total = min(*ovf_cnt, OVF_CAP);
    for (int i = 0; i < total; ++i) {
        u32t e = (u32t)ovf[i];
        if ((e >> 16) == (u32t)v)
            acc += agg1[((size_t)(e & 0xFFFFu) << 5) + c];
    }
    pairfeat[t] = acc;
}

// ---------------------------------------------------------------------------
// K7: 8 pairs per block; M1/M2 columns shared across the 8 pairs.
// ---------------------------------------------------------------------------
__global__ void k_final(const float* __restrict__ pairfeat,
                        const float* __restrict__ M1, const float* __restrict__ M2,
                        const float* __restrict__ bias,
                        float* __restrict__ out) {
    __shared__ float a1s[8][HID];
    __shared__ float a2s[8][HID];
    int i0 = blockIdx.x * 8;
    int tid = threadIdx.x;
    int p = tid >> 5, w = tid & 31;
    a1s[p][w] = pairfeat[(size_t)(i0 + p) * HID + w];
    a2s[p][w] = pairfeat[(size_t)(BATCH + i0 + p) * HID + w];
    __syncthreads();

    int c = tid;
    float acc[8];
#pragma unroll
    for (int q = 0; q < 8; ++q) acc[q] = bias[c];
#pragma unroll
    for (int k = 0; k < HID; ++k) {
        float m1 = M1[k * 256 + c];
        float m2 = M2[k * 256 + c];
#pragma unroll
        for (int q = 0; q < 8; ++q)
            acc[q] += a1s[q][k] * m1 + a2s[q][k] * m2;
    }
#pragma unroll
    for (int q = 0; q < 8; ++q)
        out[(size_t)(i0 + q) * 256 + c] = fmaxf(acc[q], 0.f);
}

// ---------------------------------------------------------------------------
extern "C" void kernel_launch(void* const* d_in, const int* in_sizes, int n_in,
                              void* d_out, int out_size, void* d_ws, size_t ws_size,
                              hipStream_t stream) {
    const int*   idx   = (const int*)d_in[0];
    const int*   src   = (const int*)d_in[1];
    const int*   dst   = (const int*)d_in[2];
    const int*   g1    = (const int*)d_in[3];
    const int*   g2    = (const int*)d_in[4];
    const float* embed = (const float*)d_in[5];
    const float* W1    = (const float*)d_in[6];
    const float* b1    = (const float*)d_in[7];
    const float* W2    = (const float*)d_in[8];
    const float* b2    = (const float*)d_in[9];
    const float* Wfc   = (const float*)d_in[10];
    const float* bfc   = (const float*)d_in[11];
    float* out = (float*)d_out;

    char* ws = (char*)d_ws;
    u16t*  tmpb     = (u16t*)ws;   ws += (size_t)NUM_EMBED * HID * 2;        // 3.5 MB
    u16t*  feat1    = (u16t*)ws;   ws += (size_t)N_NODES * HID * 2;          // 4 MB
    float* agg1     = (float*)ws;  ws += (size_t)N_NODES * HID * 4;          // 8 MB
    float* pairfeat = (float*)ws;  ws += (size_t)2 * BATCH * HID * 4;        // 1 MB
    float* M1       = (float*)ws;  ws += 32 * 256 * 4;
    float* M2       = (float*)ws;  ws += 32 * 256 * 4;
    float* bias     = (float*)ws;  ws += 256 * 4;
    u32t*  gcur     = (u32t*)ws;   ws += 256 * 4;
    u32t*  sorted   = (u32t*)ws;   ws += (size_t)NR * SEGCAP * 4;            // 4.7 MB
    int*   cnt      = (int*)ws;    ws += (size_t)N_NODES * 4;                // 256 KB
    u16t*  bins     = (u16t*)ws;   ws += (size_t)N_NODES * CAP2 * 2;         // 4 MB
    int*   ovf_cnt  = (int*)ws;    ws += 64;
    int*   ovf      = (int*)ws;    ws += (size_t)OVF_CAP * 4;                // 256 KB

    k_init<<<1, 256, 0, stream>>>(gcur, ovf_cnt);

    k_phaseA<<<NB + EMBB + 65, 256, 0, stream>>>(src, dst, gcur, sorted, ovf_cnt, ovf,
                                                 embed, W1, tmpb,
                                                 W2, b2, Wfc, bfc, M1, M2, bias);

    k_phaseB<<<NR + (N_NODES * 16) / 256, 256, 0, stream>>>(gcur, sorted, cnt, bins,
                                                            ovf_cnt, ovf,
                                                            (const u32t*)tmpb, idx,
                                                            (u32t*)feat1);

    k_spmm1<<<(N_NODES * 32) / 256, 256, 0, stream>>>(feat1, cnt, bins, ovf_cnt, ovf,
                                                      b1, agg1);
    k_spmm2b<<<(2 * BATCH * 32) / 256, 256, 0, stream>>>(agg1, cnt, bins, ovf_cnt, ovf,
                                                         g1, g2, pairfeat);

    k_final<<<BATCH / 8, 256, 0, stream>>>(pairfeat, M1, M2, bias, out);
}